// Round 3
// baseline (3723.711 us; speedup 1.0000x reference)
//
#include <hip/hip_runtime.h>

// Problem constants: B=8, C=768, NH=12, WS=8, NC=1, H=W=64
#define B_    8
#define C_    768
#define NH_   12
#define HW_   4096
#define NTOK  4097
#define MTOT  32776         // B_ * NTOK
#define NEGV  (-10000.0f)

typedef __bf16 bf16x8 __attribute__((ext_vector_type(8)));
typedef float  f32x4  __attribute__((ext_vector_type(4)));
typedef unsigned short us8 __attribute__((ext_vector_type(8)));

__device__ __forceinline__ float us2f(unsigned short u) {
    unsigned int v = ((unsigned int)u) << 16;
    float f; __builtin_memcpy(&f, &v, 4);
    return f;
}
__device__ __forceinline__ unsigned short f2us(float f) {
    unsigned int v; __builtin_memcpy(&v, &f, 4);
    v += 0x7FFFu + ((v >> 16) & 1u);   // RNE
    return (unsigned short)(v >> 16);
}

// ---------------------------------------------------------------------------
// Runtime dtype detect: fp32 N(0,1) dwords have exponent field in [64,191];
// packed bf16-pair dwords land at >=~224 or <=3. flag=1 -> inputs are fp32.
// ---------------------------------------------------------------------------
__global__ __launch_bounds__(256) void detect_dtype(
    const unsigned int* __restrict__ xw, int* __restrict__ flag)
{
    __shared__ int s[256];
    int t = threadIdx.x, cnt = 0;
    for (int i = t; i < 4096; i += 256) {
        unsigned e = (xw[i] >> 23) & 0xFFu;
        cnt += (e >= 64u && e <= 191u) ? 1 : 0;
    }
    s[t] = cnt; __syncthreads();
    for (int k = 128; k > 0; k >>= 1) { if (t < k) s[t] += s[t + k]; __syncthreads(); }
    if (t == 0) *flag = (s[0] > 2048) ? 1 : 0;
}

// ---------------------------------------------------------------------------
// qkv_wT (2304 x 768, bf16) = transpose(qkv_w (768 x 2304, flag dtype))
// ---------------------------------------------------------------------------
__global__ __launch_bounds__(256) void transpose_qkvw(
    const unsigned short* __restrict__ s16, const float* __restrict__ s32,
    const int* __restrict__ flagp, unsigned short* __restrict__ dst)
{
    int o = blockIdx.x * 256 + threadIdx.x;
    if (o >= 2304 * 768) return;
    int n = o / 768, k = o % 768;
    dst[o] = (*flagp) ? f2us(s32[(size_t)k * 2304 + n]) : s16[(size_t)k * 2304 + n];
}

// ---------------------------------------------------------------------------
// Universal GEMM: C = A(M x K) @ B + bias. A dtype via aflagp (null=bf16).
// btmode=0: B16 is Nd x K (pre-transposed bf16). btmode=1: B natural K x Nd,
// dtype via bflagp, transposed during LDS staging. Output: bf16, or fp32 if
// oflagp says so. 128x128x32 tiles, 4 waves, 16x16x32 MFMA.
// ---------------------------------------------------------------------------
#define LSTR 40   // 32+8 pad; 80 B rows, 16B-aligned

__global__ __launch_bounds__(256) void gemm_univ(
    const unsigned short* __restrict__ A16, const float* __restrict__ A32,
    const int* __restrict__ aflagp,
    const unsigned short* __restrict__ B16, const float* __restrict__ B32,
    const int* __restrict__ bflagp, int btmode,
    const unsigned short* __restrict__ bias16, const float* __restrict__ bias32,
    void* __restrict__ Cout, const int* __restrict__ oflagp,
    int M, int Nd, int K, long arow0)
{
    __shared__ __align__(16) unsigned short As[128 * LSTR];
    __shared__ __align__(16) unsigned short Bs[128 * LSTR];

    const int fa = aflagp ? *aflagp : 0;
    const int fb = bflagp ? *bflagp : 0;
    const int fo = oflagp ? *oflagp : 0;

    const int t    = threadIdx.x;
    const int m0   = blockIdx.y * 128;
    const int n0   = blockIdx.x * 128;
    const int wave = t >> 6;
    const int lane = t & 63;
    const int wm   = (wave >> 1) * 64;
    const int wn   = (wave & 1) * 64;
    const int frow = lane & 15;
    const int koff = (lane >> 4) * 8;

    f32x4 acc[4][4];
#pragma unroll
    for (int i = 0; i < 4; ++i)
#pragma unroll
        for (int j = 0; j < 4; ++j) acc[i][j] = (f32x4)0.0f;

    const int sr = t >> 2;          // 0..63
    const int sc = (t & 3) * 8;

    for (int k0 = 0; k0 < K; k0 += 32) {
        // ---- A staging ----
#pragma unroll
        for (int it = 0; it < 2; ++it) {
            int r = sr + it * 64;
            int gl = m0 + r; if (gl >= M) gl = M - 1;   // clamp (stores guarded)
            size_t grow = (size_t)(arow0 + gl);
            if (fa) {
                const float* p = &A32[grow * K + k0 + sc];
                unsigned short tmp[8];
#pragma unroll
                for (int e = 0; e < 8; ++e) tmp[e] = f2us(p[e]);
                *reinterpret_cast<us8*>(&As[r * LSTR + sc]) = *reinterpret_cast<us8*>(tmp);
            } else {
                *reinterpret_cast<bf16x8*>(&As[r * LSTR + sc]) =
                    *reinterpret_cast<const bf16x8*>(&A16[grow * K + k0 + sc]);
            }
        }
        // ---- B staging ----
        if (btmode == 0) {
#pragma unroll
            for (int it = 0; it < 2; ++it) {
                int r = sr + it * 64;
                int gn = n0 + r; if (gn >= Nd) gn = Nd - 1;
                *reinterpret_cast<bf16x8*>(&Bs[r * LSTR + sc]) =
                    *reinterpret_cast<const bf16x8*>(&B16[(size_t)gn * K + k0 + sc]);
            }
        } else {
            // natural K x Nd source; transpose into Bs[n][k]
            const int kr = t >> 3;          // 0..31
            const int nc = (t & 7) * 16;    // 0..112
            if (fb) {
                const float* p = &B32[(size_t)(k0 + kr) * Nd + n0 + nc];
#pragma unroll
                for (int e = 0; e < 16; ++e) Bs[(nc + e) * LSTR + kr] = f2us(p[e]);
            } else {
                const unsigned short* p = &B16[(size_t)(k0 + kr) * Nd + n0 + nc];
#pragma unroll
                for (int e = 0; e < 16; ++e) Bs[(nc + e) * LSTR + kr] = p[e];
            }
        }
        __syncthreads();

        bf16x8 af[4], bfr[4];
#pragma unroll
        for (int i = 0; i < 4; ++i)
            af[i] = *reinterpret_cast<const bf16x8*>(&As[(wm + i * 16 + frow) * LSTR + koff]);
#pragma unroll
        for (int j = 0; j < 4; ++j)
            bfr[j] = *reinterpret_cast<const bf16x8*>(&Bs[(wn + j * 16 + frow) * LSTR + koff]);
#pragma unroll
        for (int i = 0; i < 4; ++i)
#pragma unroll
            for (int j = 0; j < 4; ++j)
                acc[i][j] = __builtin_amdgcn_mfma_f32_16x16x32_bf16(af[i], bfr[j], acc[i][j], 0, 0, 0);
        __syncthreads();
    }

    // epilogue: C/D layout col = lane&15, row = (lane>>4)*4 + reg  [m89/m91]
    const int crow = (lane >> 4) * 4;
    const int ccol = lane & 15;
    unsigned short* C16 = (unsigned short*)Cout;
    float*          C32 = (float*)Cout;
#pragma unroll
    for (int i = 0; i < 4; ++i)
#pragma unroll
        for (int j = 0; j < 4; ++j) {
            int gn = n0 + wn + j * 16 + ccol;
            float bv = 0.0f;
            if (bias16) bv = fb ? bias32[gn] : us2f(bias16[gn]);
#pragma unroll
            for (int r = 0; r < 4; ++r) {
                int gm = m0 + wm + i * 16 + crow + r;
                if (gm < M) {
                    float v = acc[i][j][r] + bv;
                    if (fo) C32[(size_t)gm * Nd + gn] = v;
                    else    C16[(size_t)gm * Nd + gn] = f2us(v);
                }
            }
        }
}

// ---------------------------------------------------------------------------
// Window attention for one batch: block = (window, head). Reads per-batch qkv_b
// (4097 x 2304 bf16); writes image rows of xcat (in d_out, bf16).
// ---------------------------------------------------------------------------
__global__ __launch_bounds__(256) void win_attn(
    const unsigned short* __restrict__ qkvb,
    const unsigned short* __restrict__ m16, const float* __restrict__ m32,
    const int* __restrict__ flagp,
    unsigned short* __restrict__ xcat, int b)
{
    __shared__ __align__(16) unsigned short qs[64 * 64];
    __shared__ __align__(16) unsigned short ks[64 * 64];
    __shared__ __align__(16) unsigned short vs[64 * 64];
    __shared__ float S[64 * 64];
    __shared__ float tok[64];

    const int w  = blockIdx.x;        // 0..63
    const int h  = blockIdx.y;        // 0..11
    const int hb = w >> 3, wb = w & 7;
    const int t  = threadIdx.x;
    const int f  = *flagp;

#define POS(i) ((hb * 8 + ((i) >> 3)) * 64 + wb * 8 + ((i) & 7))

#pragma unroll
    for (int it = 0; it < 2; ++it) {
        int i = (t >> 3) + it * 32;
        int d = (t & 7) * 8;
        size_t row = (size_t)(1 + POS(i)) * 2304;
        *reinterpret_cast<bf16x8*>(&qs[i * 64 + d]) =
            *reinterpret_cast<const bf16x8*>(&qkvb[row + 0    + h * 64 + d]);
        *reinterpret_cast<bf16x8*>(&ks[i * 64 + d]) =
            *reinterpret_cast<const bf16x8*>(&qkvb[row + 768  + h * 64 + d]);
        *reinterpret_cast<bf16x8*>(&vs[i * 64 + d]) =
            *reinterpret_cast<const bf16x8*>(&qkvb[row + 1536 + h * 64 + d]);
    }
    if (t < 64) {
        size_t mi = ((size_t)b * HW_ + POS(t)) * C_;
        tok[t] = f ? m32[mi] : us2f(m16[mi]);
    }
    __syncthreads();

    {
        int i  = t >> 2;
        int j0 = (t & 3) * 16;
        for (int j = j0; j < j0 + 16; ++j) {
            float s = 0.f;
#pragma unroll 8
            for (int d = 0; d < 64; ++d)
                s += us2f(qs[i * 64 + d]) * us2f(ks[j * 64 + d]);
            s *= 0.125f;
            if (tok[i] * tok[j] == 0.0f) s = NEGV;
            S[i * 64 + j] = s;
        }
    }
    __syncthreads();

    if (t < 64) {
        float m = -1e30f;
        for (int j = 0; j < 64; ++j) m = fmaxf(m, S[t * 64 + j]);
        float sum = 0.f;
        for (int j = 0; j < 64; ++j) { float e = __expf(S[t * 64 + j] - m); S[t * 64 + j] = e; sum += e; }
        float inv = 1.0f / sum;
        for (int j = 0; j < 64; ++j) S[t * 64 + j] *= inv;
    }
    __syncthreads();

    {
        int i  = t >> 2;
        int d0 = (t & 3) * 16;
        size_t orow = ((size_t)(b * NTOK + 1 + POS(i))) * C_ + h * 64;
        for (int d = d0; d < d0 + 16; ++d) {
            float accv = 0.f;
#pragma unroll 8
            for (int j = 0; j < 64; ++j)
                accv += S[i * 64 + j] * us2f(vs[j * 64 + d]);
            xcat[orow + d] = f2us(accv);
        }
    }
#undef POS
}

// ---------------------------------------------------------------------------
// Cls global attention for one batch: block = head. 4096 keys from qkv_b.
// Writes cls row of xcat (d_out).
// ---------------------------------------------------------------------------
__global__ __launch_bounds__(256) void cls_attn(
    const unsigned short* __restrict__ qkvb,
    const unsigned short* __restrict__ m16, const float* __restrict__ m32,
    const unsigned short* __restrict__ g16, const float* __restrict__ g32,
    const int* __restrict__ flagp,
    unsigned short* __restrict__ xcat, int b)
{
    __shared__ float q[64];
    __shared__ float L[4096];
    __shared__ float red[256];
    __shared__ float osum[256];

    const int h = blockIdx.x, t = threadIdx.x;
    const int f = *flagp;
    if (t < 64) q[t] = us2f(qkvb[h * 64 + t]);   // row 0 = cls token
    __syncthreads();

    for (int it = 0; it < 16; ++it) {
        int j = t + it * 256;
        const unsigned short* krow = &qkvb[(size_t)(1 + j) * 2304 + 768 + h * 64];
        float s = 0.f;
#pragma unroll 8
        for (int d = 0; d < 64; ++d) s += q[d] * us2f(krow[d]);
        s *= 0.125f;
        size_t mi = ((size_t)b * HW_ + j) * C_;
        size_t gi = ((size_t)b * NH_ + h) * HW_ + j;
        float tokj = f ? m32[mi] : us2f(m16[mi]);
        float gmj  = f ? g32[gi] : us2f(g16[gi]);
        if (tokj * gmj == 0.0f) s = NEGV;
        L[j] = s;
    }
    __syncthreads();

    float m = -1e30f;
    for (int it = 0; it < 16; ++it) m = fmaxf(m, L[t + it * 256]);
    red[t] = m; __syncthreads();
    for (int s2 = 128; s2 > 0; s2 >>= 1) { if (t < s2) red[t] = fmaxf(red[t], red[t + s2]); __syncthreads(); }
    m = red[0]; __syncthreads();

    float sum = 0.f;
    for (int it = 0; it < 16; ++it) { int j = t + it * 256; float e = __expf(L[j] - m); L[j] = e; sum += e; }
    red[t] = sum; __syncthreads();
    for (int s2 = 128; s2 > 0; s2 >>= 1) { if (t < s2) red[t] += red[t + s2]; __syncthreads(); }
    const float inv = 1.0f / red[0];

    const int wv = t >> 6, l = t & 63;
    float accv = 0.f;
    for (int j = wv * 1024; j < wv * 1024 + 1024; ++j)
        accv += L[j] * us2f(qkvb[(size_t)(1 + j) * 2304 + 1536 + h * 64 + l]);
    osum[wv * 64 + l] = accv;
    __syncthreads();
    if (t < 64) {
        float v = (osum[t] + osum[64 + t] + osum[128 + t] + osum[192 + t]) * inv;
        xcat[(size_t)(b * NTOK) * C_ + h * 64 + t] = f2us(v);
    }
}

// ---------------------------------------------------------------------------
// v_cls = x_cls(bf16 cls rows of xcat) @ kv_global_w[:, C:2C]; then
// xcat image rows += v_cls broadcast (attn_b over NC=1 is identity; k_cls dead)
// ---------------------------------------------------------------------------
__global__ __launch_bounds__(256) void add_vcls(
    unsigned short* __restrict__ xcat,
    const unsigned short* __restrict__ kv16, const float* __restrict__ kv32,
    const int* __restrict__ flagp)
{
    __shared__ float xr[768];
    __shared__ float psum[4][64];
    __shared__ float vc[64];

    const int blk = blockIdx.x;
    const int b   = blk / 12;
    const int c0  = (blk % 12) * 64;
    const int t   = threadIdx.x;
    const int f   = *flagp;

    for (int it = 0; it < 3; ++it) {
        int k = t + it * 256;
        xr[k] = us2f(xcat[(size_t)(b * NTOK) * C_ + k]);
    }
    __syncthreads();

    const int cc = t & 63, kq = t >> 6;
    float p = 0.f;
    for (int k = kq * 192; k < kq * 192 + 192; ++k) {
        size_t wi = (size_t)k * 1536 + 768 + c0 + cc;
        p += xr[k] * (f ? kv32[wi] : us2f(kv16[wi]));
    }
    psum[kq][cc] = p;
    __syncthreads();
    if (t < 64) vc[t] = psum[0][t] + psum[1][t] + psum[2][t] + psum[3][t];
    __syncthreads();

    const int ch8  = (t & 7) * 8;
    const int rsub = t >> 3;
    for (int it = 0; it < 128; ++it) {
        int row = it * 32 + rsub;
        unsigned short* p8 = &xcat[(size_t)(b * NTOK + 1 + row) * C_ + c0 + ch8];
        us8 vv = *reinterpret_cast<us8*>(p8);
#pragma unroll
        for (int e = 0; e < 8; ++e)
            vv[e] = f2us(us2f(vv[e]) + vc[ch8 + e]);
        *reinterpret_cast<us8*>(p8) = vv;
    }
}

// ---------------------------------------------------------------------------
// Workspace plan (total touched = 50,344,064 B ~= out_nbytes + 128):
//   [0, 128)                flag (live whole run, never aliased)
//   [128, 18,879,104)       qkv_b  (per-batch, reused 8x)
//   [18,879,104, 22,418,048) qkv_wT (live through batch loop)
//   [128, 50,344,064)       xcatc  (copy of xcat; written AFTER the above die)
// xcat itself lives in d_out (bf16); final GEMM reads xcatc, writes d_out
// in output dtype. No write ever goes beyond ~50.35 MB into d_ws.
// ---------------------------------------------------------------------------
extern "C" void kernel_launch(void* const* d_in, const int* in_sizes, int n_in,
                              void* d_out, int out_size, void* d_ws, size_t ws_size,
                              hipStream_t stream)
{
    const unsigned short* x16    = (const unsigned short*)d_in[0];
    const float*          x32    = (const float*)d_in[0];
    const unsigned short* m16    = (const unsigned short*)d_in[1];
    const float*          m32    = (const float*)d_in[1];
    const unsigned short* g16    = (const unsigned short*)d_in[2];
    const float*          g32    = (const float*)d_in[2];
    const unsigned short* qw16   = (const unsigned short*)d_in[3];
    const float*          qw32   = (const float*)d_in[3];
    const unsigned short* kv16   = (const unsigned short*)d_in[4];
    const float*          kv32   = (const float*)d_in[4];
    const unsigned short* pw16   = (const unsigned short*)d_in[5];
    const float*          pw32   = (const float*)d_in[5];
    const unsigned short* pb16   = (const unsigned short*)d_in[6];
    const float*          pb32   = (const float*)d_in[6];

    char* ws = (char*)d_ws;
    int*            flag   = (int*)ws;
    unsigned short* qkv_b  = (unsigned short*)(ws + 128);
    unsigned short* qkv_wT = (unsigned short*)(ws + 18879104);
    unsigned short* xcatc  = (unsigned short*)(ws + 128);
    unsigned short* xcat   = (unsigned short*)d_out;   // bf16 scratch inside d_out

    // 0) dtype detect
    detect_dtype<<<1, 256, 0, stream>>>((const unsigned int*)d_in[0], flag);

    // 1) qkv_wT = transpose(qkv_w)  (bf16, 2304 x 768)
    transpose_qkvw<<<(2304 * 768 + 255) / 256, 256, 0, stream>>>(qw16, qw32, flag, qkv_wT);

    // 2) per-batch: qkv GEMM -> window attn -> cls attn
    for (int b = 0; b < B_; ++b) {
        gemm_univ<<<dim3(18, 33), 256, 0, stream>>>(
            x16, x32, flag, qkv_wT, nullptr, nullptr, 0,
            nullptr, nullptr, qkv_b, nullptr,
            NTOK, 2304, 768, (long)b * NTOK);
        win_attn<<<dim3(64, 12), 256, 0, stream>>>(qkv_b, m16, m32, flag, xcat, b);
        cls_attn<<<12, 256, 0, stream>>>(qkv_b, m16, m32, g16, g32, flag, xcat, b);
    }

    // 3) xcat image rows += v_cls broadcast
    add_vcls<<<96, 256, 0, stream>>>(xcat, kv16, kv32, flag);

    // 4) copy xcat (bf16, 50,343,936 B) out of d_out so the final GEMM can
    //    write d_out without an in-place race
    hipMemcpyAsync(xcatc, xcat, (size_t)MTOT * C_ * 2, hipMemcpyDeviceToDevice, stream);

    // 5) out = xcat @ proj_w + proj_b (B staged with in-LDS transpose from the
    //    natural K x N layout; output dtype per flag)
    gemm_univ<<<dim3(6, 257), 256, 0, stream>>>(
        xcatc, nullptr, nullptr, pw16, pw32, flag, 1,
        pb16, pb32, d_out, flag,
        MTOT, 768, 768, 0);
}

// Round 4
// 1430.967 us; speedup vs baseline: 2.6022x; 2.6022x over previous
//
#include <hip/hip_runtime.h>

// Problem constants: B=8, C=768, NH=12, WS=8, NC=1, H=W=64
#define B_    8
#define C_    768
#define NH_   12
#define HW_   4096
#define NTOK  4097
#define MTOT  32776         // B_ * NTOK
#define NEGV  (-10000.0f)
#define NSPLIT 16

typedef __bf16 bf16x8 __attribute__((ext_vector_type(8)));
typedef float  f32x4  __attribute__((ext_vector_type(4)));
typedef unsigned short us8 __attribute__((ext_vector_type(8)));

__device__ __forceinline__ float us2f(unsigned short u) {
    unsigned int v = ((unsigned int)u) << 16;
    float f; __builtin_memcpy(&f, &v, 4);
    return f;
}
__device__ __forceinline__ unsigned short f2us(float f) {
    unsigned int v; __builtin_memcpy(&v, &f, 4);
    v += 0x7FFFu + ((v >> 16) & 1u);   // RNE
    return (unsigned short)(v >> 16);
}

// ---------------------------------------------------------------------------
// Runtime dtype detect (flag=1 -> fp32 inputs). Round-3 run proved flag=0
// (bf16), but keep the dispatch: it costs ~2 us and is known-correct.
// ---------------------------------------------------------------------------
__global__ __launch_bounds__(256) void detect_dtype(
    const unsigned int* __restrict__ xw, int* __restrict__ flag)
{
    __shared__ int s[256];
    int t = threadIdx.x, cnt = 0;
    for (int i = t; i < 4096; i += 256) {
        unsigned e = (xw[i] >> 23) & 0xFFu;
        cnt += (e >= 64u && e <= 191u) ? 1 : 0;
    }
    s[t] = cnt; __syncthreads();
    for (int k = 128; k > 0; k >>= 1) { if (t < k) s[t] += s[t + k]; __syncthreads(); }
    if (t == 0) *flag = (s[0] > 2048) ? 1 : 0;
}

// ---------------------------------------------------------------------------
// qkv_wT (2304 x 768, bf16) = transpose(qkv_w (768 x 2304))
// ---------------------------------------------------------------------------
__global__ __launch_bounds__(256) void transpose_qkvw(
    const unsigned short* __restrict__ s16, const float* __restrict__ s32,
    const int* __restrict__ flagp, unsigned short* __restrict__ dst)
{
    int o = blockIdx.x * 256 + threadIdx.x;
    if (o >= 2304 * 768) return;
    int n = o / 768, k = o % 768;
    dst[o] = (*flagp) ? f2us(s32[(size_t)k * 2304 + n]) : s16[(size_t)k * 2304 + n];
}

// ---------------------------------------------------------------------------
// Universal GEMM (128x128x32 tiles, 4 waves, 16x16x32 MFMA). btmode=0: B16 is
// Nd x K bf16 (pre-transposed); btmode=1: B natural K x Nd (flag dtype),
// transposed during staging. Output bf16 or fp32 per oflagp.
// ---------------------------------------------------------------------------
#define LSTR 40   // 32+8 pad; 80 B rows, 16B-aligned

__global__ __launch_bounds__(256) void gemm_univ(
    const unsigned short* __restrict__ A16, const float* __restrict__ A32,
    const int* __restrict__ aflagp,
    const unsigned short* __restrict__ B16, const float* __restrict__ B32,
    const int* __restrict__ bflagp, int btmode,
    const unsigned short* __restrict__ bias16, const float* __restrict__ bias32,
    void* __restrict__ Cout, const int* __restrict__ oflagp,
    int M, int Nd, int K, long arow0)
{
    __shared__ __align__(16) unsigned short As[128 * LSTR];
    __shared__ __align__(16) unsigned short Bs[128 * LSTR];

    const int fa = aflagp ? *aflagp : 0;
    const int fb = bflagp ? *bflagp : 0;
    const int fo = oflagp ? *oflagp : 0;

    const int t    = threadIdx.x;
    const int m0   = blockIdx.y * 128;
    const int n0   = blockIdx.x * 128;
    const int wave = t >> 6;
    const int lane = t & 63;
    const int wm   = (wave >> 1) * 64;
    const int wn   = (wave & 1) * 64;
    const int frow = lane & 15;
    const int koff = (lane >> 4) * 8;

    f32x4 acc[4][4];
#pragma unroll
    for (int i = 0; i < 4; ++i)
#pragma unroll
        for (int j = 0; j < 4; ++j) acc[i][j] = (f32x4)0.0f;

    const int sr = t >> 2;
    const int sc = (t & 3) * 8;

    for (int k0 = 0; k0 < K; k0 += 32) {
#pragma unroll
        for (int it = 0; it < 2; ++it) {
            int r = sr + it * 64;
            int gl = m0 + r; if (gl >= M) gl = M - 1;
            size_t grow = (size_t)(arow0 + gl);
            if (fa) {
                const float* p = &A32[grow * K + k0 + sc];
                unsigned short tmp[8];
#pragma unroll
                for (int e = 0; e < 8; ++e) tmp[e] = f2us(p[e]);
                *reinterpret_cast<us8*>(&As[r * LSTR + sc]) = *reinterpret_cast<us8*>(tmp);
            } else {
                *reinterpret_cast<bf16x8*>(&As[r * LSTR + sc]) =
                    *reinterpret_cast<const bf16x8*>(&A16[grow * K + k0 + sc]);
            }
        }
        if (btmode == 0) {
#pragma unroll
            for (int it = 0; it < 2; ++it) {
                int r = sr + it * 64;
                int gn = n0 + r; if (gn >= Nd) gn = Nd - 1;
                *reinterpret_cast<bf16x8*>(&Bs[r * LSTR + sc]) =
                    *reinterpret_cast<const bf16x8*>(&B16[(size_t)gn * K + k0 + sc]);
            }
        } else {
            const int kr = t >> 3;
            const int nc = (t & 7) * 16;
            if (fb) {
                const float* p = &B32[(size_t)(k0 + kr) * Nd + n0 + nc];
#pragma unroll
                for (int e = 0; e < 16; ++e) Bs[(nc + e) * LSTR + kr] = f2us(p[e]);
            } else {
                const unsigned short* p = &B16[(size_t)(k0 + kr) * Nd + n0 + nc];
#pragma unroll
                for (int e = 0; e < 16; ++e) Bs[(nc + e) * LSTR + kr] = p[e];
            }
        }
        __syncthreads();

        bf16x8 af[4], bfr[4];
#pragma unroll
        for (int i = 0; i < 4; ++i)
            af[i] = *reinterpret_cast<const bf16x8*>(&As[(wm + i * 16 + frow) * LSTR + koff]);
#pragma unroll
        for (int j = 0; j < 4; ++j)
            bfr[j] = *reinterpret_cast<const bf16x8*>(&Bs[(wn + j * 16 + frow) * LSTR + koff]);
#pragma unroll
        for (int i = 0; i < 4; ++i)
#pragma unroll
            for (int j = 0; j < 4; ++j)
                acc[i][j] = __builtin_amdgcn_mfma_f32_16x16x32_bf16(af[i], bfr[j], acc[i][j], 0, 0, 0);
        __syncthreads();
    }

    const int crow = (lane >> 4) * 4;
    const int ccol = lane & 15;
    unsigned short* C16 = (unsigned short*)Cout;
    float*          C32 = (float*)Cout;
#pragma unroll
    for (int i = 0; i < 4; ++i)
#pragma unroll
        for (int j = 0; j < 4; ++j) {
            int gn = n0 + wn + j * 16 + ccol;
            float bv = 0.0f;
            if (bias16) bv = fb ? bias32[gn] : us2f(bias16[gn]);
#pragma unroll
            for (int r = 0; r < 4; ++r) {
                int gm = m0 + wm + i * 16 + crow + r;
                if (gm < M) {
                    float v = acc[i][j][r] + bv;
                    if (fo) C32[(size_t)gm * Nd + gn] = v;
                    else    C16[(size_t)gm * Nd + gn] = f2us(v);
                }
            }
        }
}

// ---------------------------------------------------------------------------
// Window attention over a 2-batch qkv slab: block = (window, head, bb).
// ---------------------------------------------------------------------------
__global__ __launch_bounds__(256) void win_attn(
    const unsigned short* __restrict__ qkv2,
    const unsigned short* __restrict__ m16, const float* __restrict__ m32,
    const int* __restrict__ flagp,
    unsigned short* __restrict__ xcat, int b0)
{
    __shared__ __align__(16) unsigned short qs[64 * 64];
    __shared__ __align__(16) unsigned short ks[64 * 64];
    __shared__ __align__(16) unsigned short vs[64 * 64];
    __shared__ float S[64 * 64];
    __shared__ float tok[64];

    const int w  = blockIdx.x;
    const int h  = blockIdx.y;
    const int bb = blockIdx.z;
    const int b  = b0 + bb;
    const int hb = w >> 3, wb = w & 7;
    const int t  = threadIdx.x;
    const int f  = *flagp;
    const unsigned short* qkvb = qkv2 + (size_t)bb * NTOK * 2304;

#define POS(i) ((hb * 8 + ((i) >> 3)) * 64 + wb * 8 + ((i) & 7))

#pragma unroll
    for (int it = 0; it < 2; ++it) {
        int i = (t >> 3) + it * 32;
        int d = (t & 7) * 8;
        size_t row = (size_t)(1 + POS(i)) * 2304;
        *reinterpret_cast<bf16x8*>(&qs[i * 64 + d]) =
            *reinterpret_cast<const bf16x8*>(&qkvb[row + 0    + h * 64 + d]);
        *reinterpret_cast<bf16x8*>(&ks[i * 64 + d]) =
            *reinterpret_cast<const bf16x8*>(&qkvb[row + 768  + h * 64 + d]);
        *reinterpret_cast<bf16x8*>(&vs[i * 64 + d]) =
            *reinterpret_cast<const bf16x8*>(&qkvb[row + 1536 + h * 64 + d]);
    }
    if (t < 64) {
        size_t mi = ((size_t)b * HW_ + POS(t)) * C_;
        tok[t] = f ? m32[mi] : us2f(m16[mi]);
    }
    __syncthreads();

    {
        int i  = t >> 2;
        int j0 = (t & 3) * 16;
        for (int j = j0; j < j0 + 16; ++j) {
            float s = 0.f;
#pragma unroll 8
            for (int d = 0; d < 64; ++d)
                s += us2f(qs[i * 64 + d]) * us2f(ks[j * 64 + d]);
            s *= 0.125f;
            if (tok[i] * tok[j] == 0.0f) s = NEGV;
            S[i * 64 + j] = s;
        }
    }
    __syncthreads();

    if (t < 64) {
        float m = -1e30f;
        for (int j = 0; j < 64; ++j) m = fmaxf(m, S[t * 64 + j]);
        float sum = 0.f;
        for (int j = 0; j < 64; ++j) { float e = __expf(S[t * 64 + j] - m); S[t * 64 + j] = e; sum += e; }
        float inv = 1.0f / sum;
        for (int j = 0; j < 64; ++j) S[t * 64 + j] *= inv;
    }
    __syncthreads();

    {
        int i  = t >> 2;
        int d0 = (t & 3) * 16;
        size_t orow = ((size_t)(b * NTOK + 1 + POS(i))) * C_ + h * 64;
        for (int d = d0; d < d0 + 16; ++d) {
            float accv = 0.f;
#pragma unroll 8
            for (int j = 0; j < 64; ++j)
                accv += S[i * 64 + j] * us2f(vs[j * 64 + d]);
            xcat[orow + d] = f2us(accv);
        }
    }
#undef POS
}

// ---------------------------------------------------------------------------
// Cls attention, split-K partials: block = (head, split, bb). 256 keys/block,
// one key per thread. Writes {acc[64], m, sum} per (b,h,split).
// ---------------------------------------------------------------------------
__global__ __launch_bounds__(256) void cls_part(
    const unsigned short* __restrict__ qkv2,
    const unsigned short* __restrict__ m16, const float* __restrict__ m32,
    const unsigned short* __restrict__ g16, const float* __restrict__ g32,
    const int* __restrict__ flagp,
    float* __restrict__ part,      // [B][NH][NSPLIT][68]
    int b0)
{
    __shared__ float q[64];
    __shared__ float e[256];
    __shared__ float red[256];
    __shared__ float osum[4][64];
    __shared__ float Mv, Sv;

    const int h  = blockIdx.x;
    const int sp = blockIdx.y;
    const int bb = blockIdx.z;
    const int b  = b0 + bb;
    const int t  = threadIdx.x;
    const int f  = *flagp;
    const unsigned short* qkvb = qkv2 + (size_t)bb * NTOK * 2304;

    if (t < 64) q[t] = us2f(qkvb[h * 64 + t]);   // row 0 = cls token
    __syncthreads();

    const int j = sp * 256 + t;                   // key 0..4095
    const unsigned short* krow = &qkvb[(size_t)(1 + j) * 2304 + 768 + h * 64];
    float s = 0.f;
#pragma unroll
    for (int dd = 0; dd < 8; ++dd) {
        us8 kv8 = *reinterpret_cast<const us8*>(&krow[dd * 8]);
#pragma unroll
        for (int ee = 0; ee < 8; ++ee) s += q[dd * 8 + ee] * us2f(kv8[ee]);
    }
    s *= 0.125f;
    {
        size_t mi = ((size_t)b * HW_ + j) * C_;
        size_t gi = ((size_t)b * NH_ + h) * HW_ + j;
        float tokj = f ? m32[mi] : us2f(m16[mi]);
        float gmj  = f ? g32[gi] : us2f(g16[gi]);
        if (tokj * gmj == 0.0f) s = NEGV;
    }

    red[t] = s; __syncthreads();
    for (int k2 = 128; k2 > 0; k2 >>= 1) { if (t < k2) red[t] = fmaxf(red[t], red[t + k2]); __syncthreads(); }
    const float m = red[0]; __syncthreads();

    float ev = __expf(s - m);
    e[t] = ev; red[t] = ev; __syncthreads();
    for (int k2 = 128; k2 > 0; k2 >>= 1) { if (t < k2) red[t] += red[t + k2]; __syncthreads(); }
    if (t == 0) { Mv = m; Sv = red[0]; }

    // PV: wave wv covers keys [wv*64, wv*64+64), lane = output dim
    const int wv = t >> 6, l = t & 63;
    float accv = 0.f;
    const unsigned short* vbase =
        &qkvb[(size_t)(1 + sp * 256 + wv * 64) * 2304 + 1536 + h * 64 + l];
    for (int kk = 0; kk < 64; ++kk)
        accv += e[wv * 64 + kk] * us2f(vbase[(size_t)kk * 2304]);
    osum[wv][l] = accv;
    __syncthreads();

    const size_t pi = ((size_t)(b * NH_ + h) * NSPLIT + sp) * 68;
    if (t < 64)
        part[pi + t] = osum[0][t] + osum[1][t] + osum[2][t] + osum[3][t];
    if (t == 64 + 0) part[pi + 64] = Mv;
    if (t == 64 + 1) part[pi + 65] = Sv;
}

// ---------------------------------------------------------------------------
// Combine split partials (log-sum-exp merge) -> xcat cls rows (bf16)
// ---------------------------------------------------------------------------
__global__ __launch_bounds__(64) void cls_reduce(
    const float* __restrict__ part, unsigned short* __restrict__ xcat)
{
    const int h = blockIdx.x, b = blockIdx.y, t = threadIdx.x;
    const float* pb = &part[((size_t)(b * NH_ + h) * NSPLIT) * 68];
    float gm = -1e30f;
    for (int i = 0; i < NSPLIT; ++i) gm = fmaxf(gm, pb[i * 68 + 64]);
    float S = 0.f, acc = 0.f;
    for (int i = 0; i < NSPLIT; ++i) {
        float w = __expf(pb[i * 68 + 64] - gm);
        S   += pb[i * 68 + 65] * w;
        acc += pb[i * 68 + t]  * w;
    }
    xcat[(size_t)(b * NTOK) * C_ + h * 64 + t] = f2us(acc / S);
}

// ---------------------------------------------------------------------------
// v_cls GEMV + broadcast-add, reading xcat (d_out) and writing xcatc (ws):
// replaces the 50 MB memcpy. Also copies cls rows. Grid (96, 4 row-splits).
// ---------------------------------------------------------------------------
__global__ __launch_bounds__(256) void add_vcls(
    const unsigned short* __restrict__ xcat, unsigned short* __restrict__ xcatc,
    const unsigned short* __restrict__ kv16, const float* __restrict__ kv32,
    const int* __restrict__ flagp)
{
    __shared__ float xr[768];
    __shared__ float psum[4][64];
    __shared__ float vc[64];

    const int blk = blockIdx.x;
    const int rsp = blockIdx.y;
    const int b   = blk / 12;
    const int c0  = (blk % 12) * 64;
    const int t   = threadIdx.x;
    const int f   = *flagp;

    for (int it = 0; it < 3; ++it) {
        int k = t + it * 256;
        xr[k] = us2f(xcat[(size_t)(b * NTOK) * C_ + k]);
    }
    __syncthreads();

    const int cc = t & 63, kq = t >> 6;
    float p = 0.f;
    for (int k = kq * 192; k < kq * 192 + 192; ++k) {
        size_t wi = (size_t)k * 1536 + 768 + c0 + cc;
        p += xr[k] * (f ? kv32[wi] : us2f(kv16[wi]));
    }
    psum[kq][cc] = p;
    __syncthreads();
    if (t < 64) vc[t] = psum[0][t] + psum[1][t] + psum[2][t] + psum[3][t];
    __syncthreads();

    const int ch8  = (t & 7) * 8;
    const int rsub = t >> 3;
    for (int it = 0; it < 32; ++it) {
        int row = rsp * 1024 + it * 32 + rsub;
        size_t off = (size_t)(b * NTOK + 1 + row) * C_ + c0 + ch8;
        us8 vv = *reinterpret_cast<const us8*>(&xcat[off]);
#pragma unroll
        for (int e2 = 0; e2 < 8; ++e2)
            vv[e2] = f2us(us2f(vv[e2]) + vc[ch8 + e2]);
        *reinterpret_cast<us8*>(&xcatc[off]) = vv;
    }
    if (rsp == 0 && t < 64)
        xcatc[(size_t)(b * NTOK) * C_ + c0 + t] = xcat[(size_t)(b * NTOK) * C_ + c0 + t];
}

// ---------------------------------------------------------------------------
// Workspace plan (max touched byte = 50,344,064 — proven safe in round 3):
//   [0,128)                    flag
//   [128, 37,758,080)          qkv_2b   (2-batch slab, reused 4x)
//   [37,758,080, 41,297,024)   qkv_wT   (dead after last qkv GEMM)
//   [41,297,024, 41,714,816)   cls partials (dead after cls_reduce)
//   [128, 50,344,064)          xcatc    (written by add_vcls, after all above die)
// xcat (pre-proj activations) lives in d_out until add_vcls moves it to ws.
// ---------------------------------------------------------------------------
extern "C" void kernel_launch(void* const* d_in, const int* in_sizes, int n_in,
                              void* d_out, int out_size, void* d_ws, size_t ws_size,
                              hipStream_t stream)
{
    const unsigned short* x16  = (const unsigned short*)d_in[0];
    const float*          x32  = (const float*)d_in[0];
    const unsigned short* m16  = (const unsigned short*)d_in[1];
    const float*          m32  = (const float*)d_in[1];
    const unsigned short* g16  = (const unsigned short*)d_in[2];
    const float*          g32  = (const float*)d_in[2];
    const unsigned short* qw16 = (const unsigned short*)d_in[3];
    const float*          qw32 = (const float*)d_in[3];
    const unsigned short* kv16 = (const unsigned short*)d_in[4];
    const float*          kv32 = (const float*)d_in[4];
    const unsigned short* pw16 = (const unsigned short*)d_in[5];
    const float*          pw32 = (const float*)d_in[5];
    const unsigned short* pb16 = (const unsigned short*)d_in[6];
    const float*          pb32 = (const float*)d_in[6];

    char* ws = (char*)d_ws;
    int*            flag   = (int*)ws;
    unsigned short* qkv_2b = (unsigned short*)(ws + 128);
    unsigned short* qkv_wT = (unsigned short*)(ws + 37758080);
    float*          part   = (float*)(ws + 41297024);
    unsigned short* xcatc  = (unsigned short*)(ws + 128);
    unsigned short* xcat   = (unsigned short*)d_out;

    detect_dtype<<<1, 256, 0, stream>>>((const unsigned int*)d_in[0], flag);
    transpose_qkvw<<<(2304 * 768 + 255) / 256, 256, 0, stream>>>(qw16, qw32, flag, qkv_wT);

    for (int b0 = 0; b0 < B_; b0 += 2) {
        gemm_univ<<<dim3(18, 65), 256, 0, stream>>>(
            x16, x32, flag, qkv_wT, nullptr, nullptr, 0,
            nullptr, nullptr, qkv_2b, nullptr,
            2 * NTOK, 2304, 768, (long)b0 * NTOK);
        win_attn<<<dim3(64, 12, 2), 256, 0, stream>>>(qkv_2b, m16, m32, flag, xcat, b0);
        cls_part<<<dim3(12, NSPLIT, 2), 256, 0, stream>>>(
            qkv_2b, m16, m32, g16, g32, flag, part, b0);
    }

    cls_reduce<<<dim3(12, 8), 64, 0, stream>>>(part, xcat);
    add_vcls<<<dim3(96, 4), 256, 0, stream>>>(xcat, xcatc, kv16, kv32, flag);

    gemm_univ<<<dim3(6, 257), 256, 0, stream>>>(
        xcatc, nullptr, nullptr, pw16, pw32, flag, 1,
        pb16, pb32, d_out, flag,
        MTOT, 768, 768, 0);
}